// Round 7
// baseline (193.076 us; speedup 1.0000x reference)
//
#include <hip/hip_runtime.h>

// SOM BMU: argmin_m (w_sq[m] - 2*dot(x,w[m])) -> (idx/128, idx%128).
// Filter + rescore: f16-hi-only MFMA GEMM (1/3 of split work) with provable
// error bound; candidates within MARGIN of running row-min collected into
// per-row lists; exact fp32 VALU rescore of pruned survivors picks the BMU.
// |hh - true| <= 2*2^-10*||x||*||w|| (+accum eps) ~ 0.35; MARGIN=1.5 covers.

#define B_ROWS 4096
#define M_COLS 16384
#define KF 256
#define BM 128
#define BN 128
#define NCHUNK 16
#define NSTEP 64          // 8 col-tiles * 8 k-steps (BK=32)
#define CAP 128
#define MARGIN 1.5f

typedef _Float16 f16x8 __attribute__((ext_vector_type(8)));
typedef float f32x4 __attribute__((ext_vector_type(4)));
typedef unsigned long long u64;

#define GLOAD16(gsrc, ldst) \
  __builtin_amdgcn_global_load_lds((const __attribute__((address_space(1))) void*)(gsrc), \
                                   (__attribute__((address_space(3))) void*)(ldst), 16, 0, 0)

// tile-major: tiles of 128 rows; per (tile,ks): [kch=4][r=128][kk=8] halves = 8 KB
__device__ __forceinline__ size_t tm_idx(int tile, int ks, int kch, int r) {
    return ((((size_t)(tile * 8 + ks)) * 4 + kch) * 128 + r) * 8;
}

__device__ __forceinline__ unsigned fkey(float s) {
    const unsigned fb = __float_as_uint(s);
    return (fb & 0x80000000u) ? ~fb : (fb | 0x80000000u);
}
__device__ __forceinline__ float unkey(unsigned k) {
    return (k & 0x80000000u) ? __uint_as_float(k & 0x7fffffffu) : __uint_as_float(~k);
}

// ---------------- kernel 1: split X -> tile-major f16 hi; init cnt ----------------
__global__ __launch_bounds__(256) void som_split_x(const float* __restrict__ xb,
                                                   _Float16* __restrict__ xh,
                                                   int* __restrict__ cnt) {
    const int gid = blockIdx.x * 256 + threadIdx.x;
    if (gid < B_ROWS) cnt[gid] = 0;
    const int row = gid >> 5;
    const int kg = gid & 31;
    const float4 v0 = *reinterpret_cast<const float4*>(xb + (size_t)row * KF + kg * 8);
    const float4 v1 = *reinterpret_cast<const float4*>(xb + (size_t)row * KF + kg * 8 + 4);
    const float vv[8] = {v0.x, v0.y, v0.z, v0.w, v1.x, v1.y, v1.z, v1.w};
    f16x8 h;
#pragma unroll
    for (int j = 0; j < 8; ++j) h[j] = (_Float16)vv[j];
    *reinterpret_cast<f16x8*>(xh + tm_idx(row >> 7, kg >> 2, kg & 3, row & 127)) = h;
}

// ---------------- kernel 2: split W -> tile-major f16 hi + w_sq ----------------
__global__ __launch_bounds__(256) void som_split_w(const float* __restrict__ wt,
                                                   _Float16* __restrict__ wh,
                                                   float* __restrict__ wsq) {
    const int gid = blockIdx.x * 256 + threadIdx.x;
    const int row = gid >> 5;
    const int kg = gid & 31;
    const float4 v0 = *reinterpret_cast<const float4*>(wt + (size_t)row * KF + kg * 8);
    const float4 v1 = *reinterpret_cast<const float4*>(wt + (size_t)row * KF + kg * 8 + 4);
    const float vv[8] = {v0.x, v0.y, v0.z, v0.w, v1.x, v1.y, v1.z, v1.w};
    f16x8 h;
    float s = 0.0f;
#pragma unroll
    for (int j = 0; j < 8; ++j) {
        h[j] = (_Float16)vv[j];
        s += vv[j] * vv[j];
    }
    *reinterpret_cast<f16x8*>(wh + tm_idx(row >> 7, kg >> 2, kg & 3, row & 127)) = h;
#pragma unroll
    for (int off = 16; off > 0; off >>= 1) s += __shfl_down(s, off, 64);
    if (kg == 0) wsq[row] = s;   // lanes 0 and 32 each own a row
}

// ---------------- kernel 3: hh MFMA GEMM + candidate collection ----------------
__global__ __launch_bounds__(256, 4) void som_main(const _Float16* __restrict__ xh,
                                                   const _Float16* __restrict__ wh,
                                                   const float* __restrict__ wsq,
                                                   u64* __restrict__ list,
                                                   int* __restrict__ cnt) {
    __shared__ _Float16 lds[2][2][4096];   // [buf][A,B][kch=4][r=128][8], 32 KB

    const int tid = threadIdx.x;
    const int lane = tid & 63;
    const int frow = lane & 15;
    const int kch = lane >> 4;
    const int wid = tid >> 6;
    const int wr = wid >> 1;      // wave row (0..1): 64 rows
    const int wc = wid & 1;       // wave col (0..1): 64 cols

    // bijective XCD swizzle (512 blocks, 512%8==0)
    const int id = blockIdx.x;
    const int swz = (id & 7) * 64 + (id >> 3);
    const int bx = swz & 31;      // row tile (0..31)
    const int by = swz >> 5;      // col chunk (0..15)
    const int rowbase = bx * BM;

    const int ebase = (tid & 192) * 8;   // wave-uniform LDS base (halves)
    const int tid8 = tid * 8;

    float rowmin[16];
#pragma unroll
    for (int i = 0; i < 16; ++i) rowmin[i] = 3.4e38f;

    f32x4 acc[4][4];

#define STAGE(buf_, step_) do {                                               \
    const int ct_ = (step_) >> 3, ks_ = (step_) & 7;                          \
    const size_t ab_ = (size_t)(bx * 8 + ks_) * 4096;                         \
    const size_t bb_ = (size_t)((by * 8 + ct_) * 8 + ks_) * 4096;             \
    GLOAD16(xh + ab_ + tid8,        &lds[buf_][0][ebase]);                    \
    GLOAD16(xh + ab_ + 2048 + tid8, &lds[buf_][0][2048 + ebase]);             \
    GLOAD16(wh + bb_ + tid8,        &lds[buf_][1][ebase]);                    \
    GLOAD16(wh + bb_ + 2048 + tid8, &lds[buf_][1][2048 + ebase]);             \
  } while (0)

    STAGE(0, 0);
    int buf = 0;

    for (int step = 0; step < NSTEP; ++step) {
        __syncthreads();   // stage(step) landed; everyone done reading buf^1
        if (step < NSTEP - 1) STAGE(buf ^ 1, step + 1);

        if ((step & 7) == 0) {
#pragma unroll
            for (int m = 0; m < 4; ++m)
#pragma unroll
                for (int n = 0; n < 4; ++n) acc[m][n] = (f32x4){0.f, 0.f, 0.f, 0.f};
        }

        f16x8 bh[4];
#pragma unroll
        for (int n = 0; n < 4; ++n)
            bh[n] = *reinterpret_cast<const f16x8*>(
                &lds[buf][1][kch * 1024 + (wc * 64 + n * 16 + frow) * 8]);
#pragma unroll
        for (int m = 0; m < 4; ++m) {
            const f16x8 ah = *reinterpret_cast<const f16x8*>(
                &lds[buf][0][kch * 1024 + (wr * 64 + m * 16 + frow) * 8]);
#pragma unroll
            for (int n = 0; n < 4; ++n)
                acc[m][n] = __builtin_amdgcn_mfma_f32_16x16x32_f16(ah, bh[n], acc[m][n], 0, 0, 0);
        }

        if ((step & 7) == 7) {
            // tile epilogue: scores, running row-min, margin-collect.
            // C/D layout: col=lane&15, row=(lane>>4)*4+reg
            const int colbase = by * 1024 + (step >> 3) * 128;
            float wq[4];
#pragma unroll
            for (int n = 0; n < 4; ++n) wq[n] = wsq[colbase + wc * 64 + n * 16 + frow];
#pragma unroll
            for (int m = 0; m < 4; ++m)
#pragma unroll
                for (int r = 0; r < 4; ++r) {
                    const int i = m * 4 + r;
                    float s[4];
#pragma unroll
                    for (int n = 0; n < 4; ++n) s[n] = wq[n] - 2.0f * acc[m][n][r];
                    float lmin = fminf(fminf(s[0], s[1]), fminf(s[2], s[3]));
#pragma unroll
                    for (int mk = 1; mk <= 8; mk <<= 1)
                        lmin = fminf(lmin, __shfl_xor(lmin, mk, 64));
                    rowmin[i] = fminf(rowmin[i], lmin);
                    const float thr = rowmin[i] + MARGIN;
                    const int rowg = rowbase + wr * 64 + m * 16 + kch * 4 + r;
#pragma unroll
                    for (int n = 0; n < 4; ++n) {
                        if (s[n] <= thr) {
                            const u64 p = ((u64)fkey(s[n]) << 32) |
                                          (unsigned)(colbase + wc * 64 + n * 16 + frow);
                            const int slot = atomicAdd(&cnt[rowg], 1);
                            if (slot < CAP) list[(size_t)rowg * CAP + slot] = p;
                        }
                    }
                }
        }
        buf ^= 1;
    }
#undef STAGE
}

// ---------------- kernel 4: prune + exact fp32 rescore + decode ----------------
__global__ __launch_bounds__(256) void som_rescore(const float* __restrict__ xb,
                                                   const float* __restrict__ wt,
                                                   const float* __restrict__ wsq,
                                                   const u64* __restrict__ list,
                                                   const int* __restrict__ cnt,
                                                   int* __restrict__ out) {
    const int row = (blockIdx.x * 256 + threadIdx.x) >> 6;   // one wave per row
    const int lane = threadIdx.x & 63;
    if (row >= B_ROWS) return;
    const float4 xv = *reinterpret_cast<const float4*>(xb + (size_t)row * KF + lane * 4);
    const int n = cnt[row];
    u64 best = ~0ull;
    if (n <= CAP) {
        // global hh-min over the list
        u64 kmin = ~0ull;
        for (int i = lane; i < n; i += 64) {
            const u64 p = list[(size_t)row * CAP + i];
            if (p < kmin) kmin = p;
        }
#pragma unroll
        for (int mk = 1; mk <= 32; mk <<= 1) {
            const u64 o = __shfl_xor(kmin, mk, 64);
            if (o < kmin) kmin = o;
        }
        const float thr = unkey((unsigned)(kmin >> 32)) + MARGIN;
        for (int i = 0; i < n; ++i) {
            const u64 p = list[(size_t)row * CAP + i];
            if (unkey((unsigned)(p >> 32)) > thr) continue;
            const int col = (int)(p & 0xffffffffu);
            const float4 wv = *reinterpret_cast<const float4*>(wt + (size_t)col * KF + lane * 4);
            float d = xv.x * wv.x + xv.y * wv.y + xv.z * wv.z + xv.w * wv.w;
#pragma unroll
            for (int mk = 1; mk <= 32; mk <<= 1) d += __shfl_xor(d, mk, 64);
            const float sc = wsq[col] - 2.0f * d;
            const u64 q = ((u64)fkey(sc) << 32) | (unsigned)col;
            if (q < best) best = q;
        }
    } else {
        // overflow fallback (never-path): exact scan of all candidates
        for (int col = 0; col < M_COLS; ++col) {
            const float4 wv = *reinterpret_cast<const float4*>(wt + (size_t)col * KF + lane * 4);
            float d = xv.x * wv.x + xv.y * wv.y + xv.z * wv.z + xv.w * wv.w;
#pragma unroll
            for (int mk = 1; mk <= 32; mk <<= 1) d += __shfl_xor(d, mk, 64);
            const float sc = wsq[col] - 2.0f * d;
            const u64 q = ((u64)fkey(sc) << 32) | (unsigned)col;
            if (q < best) best = q;
        }
    }
    if (lane == 0) {
        const int idx = (int)(best & 0xffffffffu);
        out[2 * row] = idx >> 7;      // idx / 128
        out[2 * row + 1] = idx & 127; // idx % 128
    }
}

extern "C" void kernel_launch(void* const* d_in, const int* in_sizes, int n_in,
                              void* d_out, int out_size, void* d_ws, size_t ws_size,
                              hipStream_t stream) {
    const float* xb = (const float*)d_in[0];   // [4096, 256] fp32
    const float* wt = (const float*)d_in[1];   // [16384, 256] fp32
    int* out = (int*)d_out;                    // [4096, 2] int32

    char* ws = (char*)d_ws;
    _Float16* xh = (_Float16*)(ws);                                    // 2 MB
    _Float16* wh = (_Float16*)(ws + (size_t)2 * 1024 * 1024);          // 8 MB
    float*   wsq = (float*)(ws + (size_t)10 * 1024 * 1024);            // 64 KB
    int*     cnt = (int*)(ws + (size_t)10 * 1024 * 1024 + 65536);      // 16 KB
    u64*    list = (u64*)(ws + (size_t)10 * 1024 * 1024 + 131072);     // 4 MB

    som_split_x<<<(B_ROWS * 32) / 256, 256, 0, stream>>>(xb, xh, cnt);
    som_split_w<<<(M_COLS * 32) / 256, 256, 0, stream>>>(wt, wh, wsq);
    som_main<<<B_ROWS / BM * NCHUNK, 256, 0, stream>>>(xh, wh, wsq, list, cnt);
    som_rescore<<<B_ROWS / 4, 256, 0, stream>>>(xb, wt, wsq, list, cnt, out);
}

// Round 8
// 158.163 us; speedup vs baseline: 1.2207x; 1.2207x over previous
//
#include <hip/hip_runtime.h>

// SOM BMU: argmin_m (w_sq[m] - 2*dot(x,w[m])) -> (idx/128, idx%128).
// Filter + rescore: f16-hi-only MFMA GEMM (error |hh-true| <~ 0.5 worst case,
// MARGIN=1.5 covers) at 256x256 tile / BK=32 / 8 waves with the measured-good
// 2-phase double-buffer loop; one collect epilogue per block (block-wide
// 256-col row-min); exact fp32 rescore of ~1-3 survivors per row.

#define B_ROWS 4096
#define M_COLS 16384
#define KF 256
#define BM 256
#define BN 256
#define NK 8              // K-steps of BK=32
#define CAP 128
#define MARGIN 1.5f

typedef _Float16 f16x8 __attribute__((ext_vector_type(8)));
typedef float f32x4 __attribute__((ext_vector_type(4)));
typedef unsigned long long u64;

#define GLOAD16(gsrc, ldst) \
  __builtin_amdgcn_global_load_lds((const __attribute__((address_space(1))) void*)(gsrc), \
                                   (__attribute__((address_space(3))) void*)(ldst), 16, 0, 0)

// tile-major: tiles of 256 rows; per (tile,ks): [kch=4][r=256][8] halves = 16 KB
__device__ __forceinline__ size_t tm_idx(int tile, int ks, int kch, int r) {
    return ((((size_t)(tile * 8 + ks)) * 4 + kch) * 256 + r) * 8;
}

__device__ __forceinline__ unsigned fkey(float s) {
    const unsigned fb = __float_as_uint(s);
    return (fb & 0x80000000u) ? ~fb : (fb | 0x80000000u);
}
__device__ __forceinline__ float unkey(unsigned k) {
    return (k & 0x80000000u) ? __uint_as_float(k & 0x7fffffffu) : __uint_as_float(~k);
}

// ---------------- kernel 1: split X -> tile-major f16 hi; init cnt ----------------
__global__ __launch_bounds__(256) void som_split_x(const float* __restrict__ xb,
                                                   _Float16* __restrict__ xh,
                                                   int* __restrict__ cnt) {
    const int gid = blockIdx.x * 256 + threadIdx.x;
    if (gid < B_ROWS) cnt[gid] = 0;
    const int row = gid >> 5;
    const int kg = gid & 31;
    const float4 v0 = *reinterpret_cast<const float4*>(xb + (size_t)row * KF + kg * 8);
    const float4 v1 = *reinterpret_cast<const float4*>(xb + (size_t)row * KF + kg * 8 + 4);
    const float vv[8] = {v0.x, v0.y, v0.z, v0.w, v1.x, v1.y, v1.z, v1.w};
    f16x8 h;
#pragma unroll
    for (int j = 0; j < 8; ++j) h[j] = (_Float16)vv[j];
    *reinterpret_cast<f16x8*>(xh + tm_idx(row >> 8, kg >> 2, kg & 3, row & 255)) = h;
}

// ---------------- kernel 2: split W -> tile-major f16 hi + w_sq ----------------
__global__ __launch_bounds__(256) void som_split_w(const float* __restrict__ wt,
                                                   _Float16* __restrict__ wh,
                                                   float* __restrict__ wsq) {
    const int gid = blockIdx.x * 256 + threadIdx.x;
    const int row = gid >> 5;
    const int kg = gid & 31;
    const float4 v0 = *reinterpret_cast<const float4*>(wt + (size_t)row * KF + kg * 8);
    const float4 v1 = *reinterpret_cast<const float4*>(wt + (size_t)row * KF + kg * 8 + 4);
    const float vv[8] = {v0.x, v0.y, v0.z, v0.w, v1.x, v1.y, v1.z, v1.w};
    f16x8 h;
    float s = 0.0f;
#pragma unroll
    for (int j = 0; j < 8; ++j) {
        h[j] = (_Float16)vv[j];
        s += vv[j] * vv[j];
    }
    *reinterpret_cast<f16x8*>(wh + tm_idx(row >> 8, kg >> 2, kg & 3, row & 255)) = h;
#pragma unroll
    for (int off = 16; off > 0; off >>= 1) s += __shfl_down(s, off, 64);
    if (kg == 0) wsq[row] = s;   // lanes 0 and 32 each own a row
}

// ---------------- kernel 3: hh MFMA GEMM (256x256) + one collect epilogue ----------------
__global__ __launch_bounds__(512) void som_main(const _Float16* __restrict__ xh,
                                                const _Float16* __restrict__ wh,
                                                const float* __restrict__ wsq,
                                                u64* __restrict__ list,
                                                int* __restrict__ cnt) {
    __shared__ _Float16 lds[2][2][8192];   // [buf][A,B][kch=4][r=256][8], 64 KB

    const int tid = threadIdx.x;
    const int lane = tid & 63;
    const int frow = lane & 15;
    const int kch = lane >> 4;
    const int wid = tid >> 6;
    const int wr = wid >> 2;      // 0..1: wave row, owns 128 rows
    const int wc = wid & 3;       // 0..3: wave col, owns 64 cols

    // bijective XCD swizzle (1024 blocks, 1024%8==0); same-XCD blocks share W col-panel
    const int bid = blockIdx.x;
    const int swz = (bid & 7) * 128 + (bid >> 3);
    const int by = swz >> 4;      // col tile 0..63
    const int bx = swz & 15;      // row tile 0..15
    const int rowbase = bx * BM;
    const int colbase = by * BN;

    const int ebase = (tid & 448) * 8;   // wave-uniform LDS base (halves)
    const int tid8 = tid * 8;

    f32x4 acc[8][4];
#pragma unroll
    for (int m = 0; m < 8; ++m)
#pragma unroll
        for (int n = 0; n < 4; ++n) acc[m][n] = (f32x4){0.f, 0.f, 0.f, 0.f};

#define STAGE(buf_, ks_) do {                                                 \
    const size_t ab_ = (size_t)(bx * 8 + (ks_)) * 8192;                       \
    const size_t bb_ = (size_t)(by * 8 + (ks_)) * 8192;                       \
    GLOAD16(xh + ab_ + tid8,        &lds[buf_][0][ebase]);                    \
    GLOAD16(xh + ab_ + 4096 + tid8, &lds[buf_][0][4096 + ebase]);             \
    GLOAD16(wh + bb_ + tid8,        &lds[buf_][1][ebase]);                    \
    GLOAD16(wh + bb_ + 4096 + tid8, &lds[buf_][1][4096 + ebase]);             \
  } while (0)

    STAGE(0, 0);
    int buf = 0;

    for (int step = 0; step < NK; ++step) {
        __syncthreads();   // stage(step) landed; everyone done reading buf^1
        if (step < NK - 1) STAGE(buf ^ 1, step + 1);

        f16x8 bh[4];
#pragma unroll
        for (int n = 0; n < 4; ++n)
            bh[n] = *reinterpret_cast<const f16x8*>(
                &lds[buf][1][kch * 2048 + (wc * 64 + n * 16 + frow) * 8]);
#pragma unroll
        for (int m = 0; m < 8; ++m) {
            const f16x8 ah = *reinterpret_cast<const f16x8*>(
                &lds[buf][0][kch * 2048 + (wr * 128 + m * 16 + frow) * 8]);
#pragma unroll
            for (int n = 0; n < 4; ++n)
                acc[m][n] = __builtin_amdgcn_mfma_f32_16x16x32_f16(ah, bh[n], acc[m][n], 0, 0, 0);
        }
        buf ^= 1;
    }
#undef STAGE

    // ---- epilogue (once per block): block-wide row-min, margin collect ----
    // C/D layout: col=lane&15, row=(lane>>4)*4+reg
    __syncthreads();                                    // LDS frag reads done
    float* redf = reinterpret_cast<float*>(&lds[0][0][0]);   // [256 rows][4 wc] = 4 KB
    float wq[4];
#pragma unroll
    for (int n = 0; n < 4; ++n) wq[n] = wsq[colbase + wc * 64 + n * 16 + frow];

#pragma unroll
    for (int m = 0; m < 8; ++m)
#pragma unroll
        for (int r = 0; r < 4; ++r) {
            float lmin = 3.4e38f;
#pragma unroll
            for (int n = 0; n < 4; ++n)
                lmin = fminf(lmin, wq[n] - 2.0f * acc[m][n][r]);
#pragma unroll
            for (int mk = 1; mk <= 8; mk <<= 1)
                lmin = fminf(lmin, __shfl_xor(lmin, mk, 64));
            if (frow == 0)
                redf[(wr * 128 + m * 16 + kch * 4 + r) * 4 + wc] = lmin;
        }
    __syncthreads();

#pragma unroll
    for (int m = 0; m < 8; ++m)
#pragma unroll
        for (int r = 0; r < 4; ++r) {
            const int rl = wr * 128 + m * 16 + kch * 4 + r;
            const float bmin = fminf(fminf(redf[rl * 4], redf[rl * 4 + 1]),
                                     fminf(redf[rl * 4 + 2], redf[rl * 4 + 3]));
            const float thr = bmin + MARGIN;
            const int rowg = rowbase + rl;
#pragma unroll
            for (int n = 0; n < 4; ++n) {
                const float s = wq[n] - 2.0f * acc[m][n][r];
                if (s <= thr) {
                    const u64 p = ((u64)fkey(s) << 32) |
                                  (unsigned)(colbase + wc * 64 + n * 16 + frow);
                    const int slot = atomicAdd(&cnt[rowg], 1);
                    if (slot < CAP) list[(size_t)rowg * CAP + slot] = p;
                }
            }
        }
}

// ---------------- kernel 4: prune + exact fp32 rescore + decode ----------------
__global__ __launch_bounds__(256) void som_rescore(const float* __restrict__ xb,
                                                   const float* __restrict__ wt,
                                                   const float* __restrict__ wsq,
                                                   const u64* __restrict__ list,
                                                   const int* __restrict__ cnt,
                                                   int* __restrict__ out) {
    const int row = (blockIdx.x * 256 + threadIdx.x) >> 6;   // one wave per row
    const int lane = threadIdx.x & 63;
    if (row >= B_ROWS) return;
    const float4 xv = *reinterpret_cast<const float4*>(xb + (size_t)row * KF + lane * 4);
    const int n = cnt[row];
    u64 best = ~0ull;
    if (n <= CAP) {
        // global hh-min key over the list
        u64 kmin = ~0ull;
        for (int i = lane; i < n; i += 64) {
            const u64 p = list[(size_t)row * CAP + i];
            if (p < kmin) kmin = p;
        }
#pragma unroll
        for (int mk = 1; mk <= 32; mk <<= 1) {
            const u64 o = __shfl_xor(kmin, mk, 64);
            if (o < kmin) kmin = o;
        }
        const float thr = unkey((unsigned)(kmin >> 32)) + MARGIN;
        // lane-parallel prune, ballot survivors, wave-dot each survivor
        for (int base = 0; base < n; base += 64) {
            const int i = base + lane;
            u64 p = ~0ull;
            bool keep = false;
            if (i < n) {
                p = list[(size_t)row * CAP + i];
                keep = unkey((unsigned)(p >> 32)) <= thr;
            }
            unsigned long long mask = __ballot(keep);
            while (mask) {
                const int src = __ffsll((unsigned long long)mask) - 1;
                mask &= mask - 1;
                const int col = (int)(__shfl(p, src, 64) & 0xffffffffu);
                const float4 wv = *reinterpret_cast<const float4*>(wt + (size_t)col * KF + lane * 4);
                float d = xv.x * wv.x + xv.y * wv.y + xv.z * wv.z + xv.w * wv.w;
#pragma unroll
                for (int mk = 1; mk <= 32; mk <<= 1) d += __shfl_xor(d, mk, 64);
                const float sc = wsq[col] - 2.0f * d;
                const u64 q = ((u64)fkey(sc) << 32) | (unsigned)col;
                if (q < best) best = q;
            }
        }
    } else {
        // overflow fallback (never-path): exact scan of all candidates
        for (int col = 0; col < M_COLS; ++col) {
            const float4 wv = *reinterpret_cast<const float4*>(wt + (size_t)col * KF + lane * 4);
            float d = xv.x * wv.x + xv.y * wv.y + xv.z * wv.z + xv.w * wv.w;
#pragma unroll
            for (int mk = 1; mk <= 32; mk <<= 1) d += __shfl_xor(d, mk, 64);
            const float sc = wsq[col] - 2.0f * d;
            const u64 q = ((u64)fkey(sc) << 32) | (unsigned)col;
            if (q < best) best = q;
        }
    }
    if (lane == 0) {
        const int idx = (int)(best & 0xffffffffu);
        out[2 * row] = idx >> 7;      // idx / 128
        out[2 * row + 1] = idx & 127; // idx % 128
    }
}

extern "C" void kernel_launch(void* const* d_in, const int* in_sizes, int n_in,
                              void* d_out, int out_size, void* d_ws, size_t ws_size,
                              hipStream_t stream) {
    const float* xb = (const float*)d_in[0];   // [4096, 256] fp32
    const float* wt = (const float*)d_in[1];   // [16384, 256] fp32
    int* out = (int*)d_out;                    // [4096, 2] int32

    char* ws = (char*)d_ws;
    _Float16* xh = (_Float16*)(ws);                                    // 2 MB
    _Float16* wh = (_Float16*)(ws + (size_t)2 * 1024 * 1024);          // 8 MB
    float*   wsq = (float*)(ws + (size_t)10 * 1024 * 1024);            // 64 KB
    int*     cnt = (int*)(ws + (size_t)10 * 1024 * 1024 + 65536);      // 16 KB
    u64*    list = (u64*)(ws + (size_t)10 * 1024 * 1024 + 131072);     // 4 MB

    som_split_x<<<(B_ROWS * 32) / 256, 256, 0, stream>>>(xb, xh, cnt);
    som_split_w<<<(M_COLS * 32) / 256, 256, 0, stream>>>(wt, wh, wsq);
    som_main<<<(B_ROWS / BM) * (M_COLS / BN), 512, 0, stream>>>(xh, wh, wsq, list, cnt);
    som_rescore<<<B_ROWS / 4, 256, 0, stream>>>(xb, wt, wsq, list, cnt, out);
}

// Round 9
// 107.586 us; speedup vs baseline: 1.7946x; 1.4701x over previous
//
#include <hip/hip_runtime.h>

// SOM BMU: argmin_m (w_sq[m] - 2*dot(x,w[m])) -> (idx/128, idx%128).
// Two-phase filter + exact rescore, all hh (f16-hi) MFMA:
//   A: hh-GEMM -> exact per-row hh-min (u32 fkey atomicMin, no lists)
//   B: hh-GEMM again -> collect cols with s <= gmin + MARGIN (~1/row)
//   C: exact fp32 rescore of survivors + decode
// |hh - true| <= 2^-10*||x||*||w|| *2 ~ 0.5 << MARGIN=1.5 (certified cover).
// GEMM shape: 128x128 coltile, 4 waves, BK=64 (32 MFMA/wave/step), 64KB dbuf
// LDS, acc[4][4] (64 VGPR) -> NO accumulator spill (rounds 5-8 lesson).

#define B_ROWS 4096
#define M_COLS 16384
#define KF 256
#define BM 128
#define NCHUNK 16
#define NSTEP 32          // 8 coltiles * 4 k-steps (BK=64)
#define CAP 64
#define MARGIN 1.5f

typedef _Float16 f16x8 __attribute__((ext_vector_type(8)));
typedef float f32x4 __attribute__((ext_vector_type(4)));
typedef unsigned long long u64;

#define GLOAD16(gsrc, ldst) \
  __builtin_amdgcn_global_load_lds((const __attribute__((address_space(1))) void*)(gsrc), \
                                   (__attribute__((address_space(3))) void*)(ldst), 16, 0, 0)

// tile-major: tiles of 128 rows; per (tile,ks32): [kch=4][r=128][8] halves = 8KB
__device__ __forceinline__ size_t tm_idx(int tile, int ks, int kch, int r) {
    return ((((size_t)(tile * 8 + ks)) * 4 + kch) * 128 + r) * 8;
}

__device__ __forceinline__ unsigned fkey(float s) {
    const unsigned fb = __float_as_uint(s);
    return (fb & 0x80000000u) ? ~fb : (fb | 0x80000000u);
}
__device__ __forceinline__ float unkey(unsigned k) {
    return (k & 0x80000000u) ? __uint_as_float(k & 0x7fffffffu) : __uint_as_float(~k);
}

// ---------------- kernel 1: split X -> tile-major f16 hi; init gkey/cnt ----------------
__global__ __launch_bounds__(256) void som_split_x(const float* __restrict__ xb,
                                                   _Float16* __restrict__ xh,
                                                   unsigned* __restrict__ gkey,
                                                   unsigned* __restrict__ cnt) {
    const int gid = blockIdx.x * 256 + threadIdx.x;
    if (gid < B_ROWS) { gkey[gid] = 0xFFFFFFFFu; cnt[gid] = 0u; }
    const int row = gid >> 5;
    const int kg = gid & 31;
    const float4 v0 = *reinterpret_cast<const float4*>(xb + (size_t)row * KF + kg * 8);
    const float4 v1 = *reinterpret_cast<const float4*>(xb + (size_t)row * KF + kg * 8 + 4);
    const float vv[8] = {v0.x, v0.y, v0.z, v0.w, v1.x, v1.y, v1.z, v1.w};
    f16x8 h;
#pragma unroll
    for (int j = 0; j < 8; ++j) h[j] = (_Float16)vv[j];
    *reinterpret_cast<f16x8*>(xh + tm_idx(row >> 7, kg >> 2, kg & 3, row & 127)) = h;
}

// ---------------- kernel 2: split W -> tile-major f16 hi + w_sq ----------------
__global__ __launch_bounds__(256) void som_split_w(const float* __restrict__ wt,
                                                   _Float16* __restrict__ wh,
                                                   float* __restrict__ wsq) {
    const int gid = blockIdx.x * 256 + threadIdx.x;
    const int row = gid >> 5;
    const int kg = gid & 31;
    const float4 v0 = *reinterpret_cast<const float4*>(wt + (size_t)row * KF + kg * 8);
    const float4 v1 = *reinterpret_cast<const float4*>(wt + (size_t)row * KF + kg * 8 + 4);
    const float vv[8] = {v0.x, v0.y, v0.z, v0.w, v1.x, v1.y, v1.z, v1.w};
    f16x8 h;
    float s = 0.0f;
#pragma unroll
    for (int j = 0; j < 8; ++j) {
        h[j] = (_Float16)vv[j];
        s += vv[j] * vv[j];
    }
    *reinterpret_cast<f16x8*>(wh + tm_idx(row >> 7, kg >> 2, kg & 3, row & 127)) = h;
#pragma unroll
    for (int off = 16; off > 0; off >>= 1) s += __shfl_down(s, off, 64);
    if (kg == 0) wsq[row] = s;   // lanes 0 and 32 each own a row
}

// ---------------- kernel 3: hh GEMM, MODE 0 = row-min, MODE 1 = collect ----------------
template <int MODE>
__global__ __launch_bounds__(256, 2) void som_gemm(const _Float16* __restrict__ xh,
                                                   const _Float16* __restrict__ wh,
                                                   const float* __restrict__ wsq,
                                                   unsigned* __restrict__ gkey,
                                                   unsigned* __restrict__ cnt,
                                                   unsigned* __restrict__ list) {
    __shared__ _Float16 lds[2][2][8192];   // [buf][A,B][kk=2][kch=4][r=128][8], 64 KB

    const int tid = threadIdx.x;
    const int lane = tid & 63;
    const int frow = lane & 15;
    const int kch = lane >> 4;
    const int wid = tid >> 6;
    const int wr = wid >> 1;      // wave row (0..1): 64 rows
    const int wc = wid & 1;       // wave col (0..1): 64 cols

    // bijective XCD swizzle (512 blocks, 512%8==0)
    const int id = blockIdx.x;
    const int swz = (id & 7) * 64 + (id >> 3);
    const int bx = swz & 31;      // row tile (0..31)
    const int by = swz >> 5;      // col chunk (0..15)
    const int rowbase = bx * BM;

    const int ebase = (tid & 192) * 8;   // wave-uniform LDS base (halves)
    const int tid8 = tid * 8;

    float rowbest[16];
    float thrreg[16];
#pragma unroll
    for (int i = 0; i < 16; ++i) {
        rowbest[i] = 3.4e38f;
        if (MODE == 1)
            thrreg[i] = unkey(gkey[rowbase + wr * 64 + (i >> 2) * 16 + kch * 4 + (i & 3)]) + MARGIN;
    }

    f32x4 acc[4][4];

#define STAGE(buf_, step_) do {                                               \
    const int ct_ = (step_) >> 2, t_ = (step_) & 3;                           \
    const size_t ab_ = (size_t)(bx * 8 + 2 * t_) * 4096;                      \
    const size_t bb_ = (size_t)((by * 8 + ct_) * 8 + 2 * t_) * 4096;          \
    GLOAD16(xh + ab_ + tid8,        &lds[buf_][0][ebase]);                    \
    GLOAD16(xh + ab_ + 2048 + tid8, &lds[buf_][0][2048 + ebase]);             \
    GLOAD16(xh + ab_ + 4096 + tid8, &lds[buf_][0][4096 + ebase]);             \
    GLOAD16(xh + ab_ + 6144 + tid8, &lds[buf_][0][6144 + ebase]);             \
    GLOAD16(wh + bb_ + tid8,        &lds[buf_][1][ebase]);                    \
    GLOAD16(wh + bb_ + 2048 + tid8, &lds[buf_][1][2048 + ebase]);             \
    GLOAD16(wh + bb_ + 4096 + tid8, &lds[buf_][1][4096 + ebase]);             \
    GLOAD16(wh + bb_ + 6144 + tid8, &lds[buf_][1][6144 + ebase]);             \
  } while (0)

    STAGE(0, 0);
    int buf = 0;

    for (int step = 0; step < NSTEP; ++step) {
        __syncthreads();   // stage(step) landed; everyone done reading buf^1
        if (step < NSTEP - 1) STAGE(buf ^ 1, step + 1);

        if ((step & 3) == 0) {
#pragma unroll
            for (int m = 0; m < 4; ++m)
#pragma unroll
                for (int n = 0; n < 4; ++n) acc[m][n] = (f32x4){0.f, 0.f, 0.f, 0.f};
        }

#pragma unroll
        for (int kk = 0; kk < 2; ++kk) {
            f16x8 bh[4];
#pragma unroll
            for (int n = 0; n < 4; ++n)
                bh[n] = *reinterpret_cast<const f16x8*>(
                    &lds[buf][1][kk * 4096 + kch * 1024 + (wc * 64 + n * 16 + frow) * 8]);
#pragma unroll
            for (int m = 0; m < 4; ++m) {
                const f16x8 ah = *reinterpret_cast<const f16x8*>(
                    &lds[buf][0][kk * 4096 + kch * 1024 + (wr * 64 + m * 16 + frow) * 8]);
#pragma unroll
                for (int n = 0; n < 4; ++n)
                    acc[m][n] = __builtin_amdgcn_mfma_f32_16x16x32_f16(ah, bh[n], acc[m][n], 0, 0, 0);
            }
        }

        if ((step & 3) == 3) {
            // coltile epilogue. C/D layout: col=lane&15, row=(lane>>4)*4+reg
            const int ct = step >> 2;
            const int cb = by * 1024 + ct * 128 + wc * 64 + frow;
            float wq[4];
#pragma unroll
            for (int n = 0; n < 4; ++n) wq[n] = wsq[cb + n * 16];
#pragma unroll
            for (int i = 0; i < 16; ++i) {
                const int m = i >> 2, r = i & 3;
                float s[4];
#pragma unroll
                for (int n = 0; n < 4; ++n) s[n] = wq[n] - 2.0f * acc[m][n][r];
                if (MODE == 0) {
                    float sm = fminf(fminf(s[0], s[1]), fminf(s[2], s[3]));
#pragma unroll
                    for (int mk = 1; mk <= 8; mk <<= 1)
                        sm = fminf(sm, __shfl_xor(sm, mk, 64));
                    rowbest[i] = fminf(rowbest[i], sm);
                } else {
                    const int rowg = rowbase + wr * 64 + m * 16 + kch * 4 + r;
#pragma unroll
                    for (int n = 0; n < 4; ++n) {
                        if (s[n] <= thrreg[i]) {
                            const unsigned slot = atomicAdd(&cnt[rowg], 1u);
                            if (slot < CAP) list[(size_t)rowg * CAP + slot] = (unsigned)(cb + n * 16);
                        }
                    }
                }
            }
        }
        buf ^= 1;
    }
#undef STAGE

    if (MODE == 0) {
        // cross-wave (wc) min in LDS, then one atomicMin per row
        __syncthreads();
        float* red = reinterpret_cast<float*>(&lds[0][0][0]);   // [128][2]
#pragma unroll
        for (int i = 0; i < 16; ++i)
            if (frow == 0)
                red[(wr * 64 + (i >> 2) * 16 + kch * 4 + (i & 3)) * 2 + wc] = rowbest[i];
        __syncthreads();
        if (tid < BM)
            atomicMin(&gkey[rowbase + tid], fkey(fminf(red[tid * 2], red[tid * 2 + 1])));
    }
}

// ---------------- kernel 4: exact fp32 rescore + decode ----------------
__global__ __launch_bounds__(256) void som_rescore(const float* __restrict__ xb,
                                                   const float* __restrict__ wt,
                                                   const float* __restrict__ wsq,
                                                   const unsigned* __restrict__ list,
                                                   const unsigned* __restrict__ cnt,
                                                   int* __restrict__ out) {
    const int row = (blockIdx.x * 256 + threadIdx.x) >> 6;   // one wave per row
    const int lane = threadIdx.x & 63;
    if (row >= B_ROWS) return;
    const float4 xv = *reinterpret_cast<const float4*>(xb + (size_t)row * KF + lane * 4);
    const unsigned n = cnt[row];
    u64 best = ~0ull;
    if (n <= CAP) {
        for (unsigned i = 0; i < n; ++i) {
            const int col = (int)list[(size_t)row * CAP + i];
            const float4 wv = *reinterpret_cast<const float4*>(wt + (size_t)col * KF + lane * 4);
            float d = xv.x * wv.x + xv.y * wv.y + xv.z * wv.z + xv.w * wv.w;
#pragma unroll
            for (int mk = 1; mk <= 32; mk <<= 1) d += __shfl_xor(d, mk, 64);
            const float sc = wsq[col] - 2.0f * d;
            const u64 q = ((u64)fkey(sc) << 32) | (unsigned)col;
            if (q < best) best = q;
        }
    } else {
        // overflow fallback (never-path): exact scan of all candidates
        for (int col = 0; col < M_COLS; ++col) {
            const float4 wv = *reinterpret_cast<const float4*>(wt + (size_t)col * KF + lane * 4);
            float d = xv.x * wv.x + xv.y * wv.y + xv.z * wv.z + xv.w * wv.w;
#pragma unroll
            for (int mk = 1; mk <= 32; mk <<= 1) d += __shfl_xor(d, mk, 64);
            const float sc = wsq[col] - 2.0f * d;
            const u64 q = ((u64)fkey(sc) << 32) | (unsigned)col;
            if (q < best) best = q;
        }
    }
    if (lane == 0) {
        const int idx = (int)(best & 0xffffffffu);
        out[2 * row] = idx >> 7;      // idx / 128
        out[2 * row + 1] = idx & 127; // idx % 128
    }
}

extern "C" void kernel_launch(void* const* d_in, const int* in_sizes, int n_in,
                              void* d_out, int out_size, void* d_ws, size_t ws_size,
                              hipStream_t stream) {
    const float* xb = (const float*)d_in[0];   // [4096, 256] fp32
    const float* wt = (const float*)d_in[1];   // [16384, 256] fp32
    int* out = (int*)d_out;                    // [4096, 2] int32

    char* ws = (char*)d_ws;
    _Float16* xh  = (_Float16*)(ws);                                   // 2 MB
    _Float16* wh  = (_Float16*)(ws + (size_t)2 * 1024 * 1024);         // 8 MB
    float*    wsq = (float*)(ws + (size_t)10 * 1024 * 1024);           // 64 KB
    unsigned* gkey = (unsigned*)(ws + (size_t)10 * 1024 * 1024 + 65536);   // 16 KB
    unsigned* cnt  = (unsigned*)(ws + (size_t)10 * 1024 * 1024 + 81920);   // 16 KB
    unsigned* list = (unsigned*)(ws + (size_t)10 * 1024 * 1024 + 131072);  // 1 MB

    som_split_x<<<(B_ROWS * 32) / 256, 256, 0, stream>>>(xb, xh, gkey, cnt);
    som_split_w<<<(M_COLS * 32) / 256, 256, 0, stream>>>(wt, wh, wsq);
    som_gemm<0><<<BM * NCHUNK / 4, 256, 0, stream>>>(xh, wh, wsq, gkey, cnt, list);
    som_gemm<1><<<BM * NCHUNK / 4, 256, 0, stream>>>(xh, wh, wsq, gkey, cnt, list);
    som_rescore<<<B_ROWS / 4, 256, 0, stream>>>(xb, wt, wsq, list, cnt, out);
}